// Round 13
// baseline (146.556 us; speedup 1.0000x reference)
//
#include <hip/hip_runtime.h>
#include <stdint.h>

// ---------- types ----------
typedef __bf16 bf16x8 __attribute__((ext_vector_type(8)));
typedef float  f32x4  __attribute__((ext_vector_type(4)));
typedef unsigned short us4n __attribute__((ext_vector_type(4)));   // native vec for nt stores

__device__ __forceinline__ unsigned short f2bf(float f) {
  union { float f; unsigned int u; } v; v.f = f;
  unsigned int r = v.u + 0x7FFFu + ((v.u >> 16) & 1u);   // RNE
  return (unsigned short)(r >> 16);
}
__device__ __forceinline__ float bf2f(unsigned short b) {
  union { unsigned int u; float f; } v; v.u = ((unsigned int)b) << 16; return v.f;
}

// ---- fp8 e4m3 (OCP) encode/decode, RNE ----
__device__ __forceinline__ unsigned char f2fp8(float f) {
  f = fminf(fmaxf(f, -448.f), 448.f);
  union { float f; unsigned u; } v; v.f = f;
  unsigned s = (v.u >> 24) & 0x80;
  int e = (v.u >> 23) & 0xFF;
  unsigned m = v.u & 0x7FFFFF;
  if (e >= 121) {                       // normal
    unsigned keep = m >> 20, rest = m & 0xFFFFF;
    unsigned v8 = ((unsigned)(e - 120) << 3) | keep;
    v8 += (rest > 0x80000u) || (rest == 0x80000u && (keep & 1));
    if (v8 > 0x7E) v8 = 0x7E;           // avoid NaN encoding
    return (unsigned char)(s | v8);
  }
  if (e <= 110) return (unsigned char)s;  // rounds to 0
  unsigned M = 0x800000u | m;
  int shift = 141 - e;                  // 21..30
  unsigned keep = M >> shift;
  unsigned rest = M & ((1u << shift) - 1);
  unsigned half = 1u << (shift - 1);
  keep += (rest > half) || (rest == half && (keep & 1));
  return (unsigned char)(s | keep);
}
__device__ __forceinline__ float fp82f(unsigned char b) {
  unsigned s = (b & 0x80) ? 0x80000000u : 0u;
  int E = (b >> 3) & 0xF;
  unsigned m = b & 7;
  union { unsigned u; float f; } t;
  if (E == 0) t.f = (float)m * 0.001953125f;   // m * 2^-9
  else t.u = ((unsigned)(E + 120) << 23) | (m << 20);
  t.u |= s;
  return t.f;
}

__device__ __forceinline__ void gld_lds16(const void* g, void* l) {
  __builtin_amdgcn_global_load_lds(
      (const __attribute__((address_space(1))) void*)g,
      (__attribute__((address_space(3))) void*)l, 16, 0, 0);
}

__device__ __forceinline__ int swz(int row) { return (row & 3) ^ ((row >> 2) & 3); }

// fragment-linear address (elements): fragment (row>>4, k>>5) = 64 lanes x 8 elems,
// lane = ((k>>3)&3)*16 + (row&15)  ->  wave fragment load = base + lane*8, coalesced
__device__ __forceinline__ long g8f_addr(long row, long k) {
  return (row >> 4) * 16384 + (k >> 5) * 512 + ((((k >> 3) & 3) * 16) + (row & 15)) * 8 + (k & 7);
}

// ---------- convert: Y -> Ybf (bf16 fragment-linear) + Ybt (bf16 transposed);
// W -> Wbf (bf16 fragment-linear); y==16,x==0 zeros stats ----------
__global__ __launch_bounds__(256) void convert_all(
    const float* __restrict__ Y, unsigned short* __restrict__ Ybf,
    unsigned short* __restrict__ Ybt, const float* __restrict__ W,
    unsigned short* __restrict__ Wbf, float* __restrict__ stats) {
  if (blockIdx.y == 16) {   // W: 64 blocks, each one 16-row group (32 KB out)
    if (blockIdx.x == 0) {  // zero diag(4096f)+l(4096f)+flags(64u)
      for (int i = threadIdx.x; i < 8256; i += 256) ((unsigned int*)stats)[i] = 0u;
    }
    const int rg = blockIdx.x;
#pragma unroll
    for (int j = 0; j < 8; j++) {
      const int c = j * 256 + threadIdx.x;     // 2048 chunks
      const int f = c >> 6, lf = c & 63;
      const int row = rg * 16 + (lf & 15);
      const int kk = f * 32 + (lf >> 4) * 8;
      const float* src = W + (long)row * 1024 + kk;
      ushort4 o0, o1;
      o0.x = f2bf(src[0]); o0.y = f2bf(src[1]); o0.z = f2bf(src[2]); o0.w = f2bf(src[3]);
      o1.x = f2bf(src[4]); o1.y = f2bf(src[5]); o1.z = f2bf(src[6]); o1.w = f2bf(src[7]);
      unsigned short* dst = Wbf + (long)rg * 16384 + f * 512 + lf * 8;
      *(ushort4*)dst = o0;
      *(ushort4*)(dst + 4) = o1;
    }
    return;
  }
  __shared__ unsigned short tile[64][65];
  const int r0 = blockIdx.x * 64;
  const int c0 = blockIdx.y * 64;
  const int tx = threadIdx.x & 63, ty = threadIdx.x >> 6;
#pragma unroll
  for (int k = 0; k < 16; k++) {
    const int r = ty + 4 * k;
    tile[r][tx] = f2bf(Y[(long)(r0 + r) * 1024 + c0 + tx]);
  }
  __syncthreads();
  // Ybt (row-major transposed, for gemm3's B operand)
#pragma unroll
  for (int k = 0; k < 16; k++) {
    const int c = ty + 4 * k;
    Ybt[(long)(c0 + c) * 4096 + r0 + tx] = tile[tx][c];
  }
  // Ybf fragment-linear: 8 fragments (rgl 0..3 x kfl 0..1) = 512 chunks of 16 B
#pragma unroll
  for (int j = 0; j < 2; j++) {
    const int c = j * 256 + threadIdx.x;
    const int f = c >> 6, lf = c & 63;
    const int rgl = f >> 1, kfl = f & 1;
    const int row = rgl * 16 + (lf & 15);
    const int kk = kfl * 32 + (lf >> 4) * 8;
    ushort4 o0, o1;
    o0.x = tile[row][kk + 0]; o0.y = tile[row][kk + 1];
    o0.z = tile[row][kk + 2]; o0.w = tile[row][kk + 3];
    o1.x = tile[row][kk + 4]; o1.y = tile[row][kk + 5];
    o1.z = tile[row][kk + 6]; o1.w = tile[row][kk + 7];
    unsigned short* dst = Ybf + ((long)(r0 >> 4) + rgl) * 16384 + ((long)(c0 >> 5) + kfl) * 512 + lf * 8;
    *(ushort4*)dst = o0;
    *(ushort4*)(dst + 4) = o1;
  }
}

// ---------- GEMM1 barrier-free: G8f = fp8(Y W^T) + diag; coalesced fragment loads ----------
// 128x64 tile, 4 waves (2x2), wave = 64x32 via 4x2 MFMA bf16; depth-4 register pipeline.
__global__ __launch_bounds__(256) void gemm1_fused(
    const unsigned short* __restrict__ Ybf, const unsigned short* __restrict__ Wbf,
    unsigned char* __restrict__ G8, float* __restrict__ diag) {
  const int tid = threadIdx.x, lane = tid & 63, wave = tid >> 6;
  const int waveM = wave >> 1, waveN = wave & 1;
  const long rowA0 = (long)blockIdx.y * 128;
  const long rowB0 = (long)blockIdx.x * 64;

  const unsigned short* pA[4];
  const unsigned short* pB[2];
#pragma unroll
  for (int i = 0; i < 4; i++)
    pA[i] = Ybf + ((rowA0 >> 4) + waveM * 4 + i) * 16384 + lane * 8;
#pragma unroll
  for (int j = 0; j < 2; j++)
    pB[j] = Wbf + ((rowB0 >> 4) + waveN * 2 + j) * 16384 + lane * 8;

  f32x4 acc[4][2];
#pragma unroll
  for (int i = 0; i < 4; i++)
#pragma unroll
    for (int j = 0; j < 2; j++)
#pragma unroll
      for (int r = 0; r < 4; r++) acc[i][j][r] = 0.f;

  bf16x8 fa[4][4], fb[4][2];
#pragma unroll
  for (int p = 0; p < 4; p++) {
#pragma unroll
    for (int i = 0; i < 4; i++) fa[p][i] = *(const bf16x8*)(pA[i] + p * 512);
#pragma unroll
    for (int j = 0; j < 2; j++) fb[p][j] = *(const bf16x8*)(pB[j] + p * 512);
  }

  for (int it = 0; it < 32; it += 4) {
#pragma unroll
    for (int p = 0; p < 4; p++) {
#pragma unroll
      for (int mi = 0; mi < 4; mi++)
#pragma unroll
        for (int ni = 0; ni < 2; ni++)
          acc[mi][ni] = __builtin_amdgcn_mfma_f32_16x16x32_bf16(fa[p][mi], fb[p][ni], acc[mi][ni], 0, 0, 0);
      const int kn = (it + p + 4) * 512;   // tail over-read lands in adjacent ws (unused)
#pragma unroll
      for (int i = 0; i < 4; i++) fa[p][i] = *(const bf16x8*)(pA[i] + kn);
#pragma unroll
      for (int j = 0; j < 2; j++) fb[p][j] = *(const bf16x8*)(pB[j] + kn);
    }
  }

  const long row0 = rowA0 + waveM * 64 + (lane >> 4) * 4;
  const long col0 = rowB0 + waveN * 32 + (lane & 15);
  float nsum[4][4];
#pragma unroll
  for (int mi = 0; mi < 4; mi++)
#pragma unroll
    for (int r = 0; r < 4; r++) nsum[mi][r] = 0.f;
#pragma unroll
  for (int mi = 0; mi < 4; mi++)
#pragma unroll
    for (int ni = 0; ni < 2; ni++)
#pragma unroll
      for (int r = 0; r < 4; r++) {
        unsigned char q8 = f2fp8(acc[mi][ni][r]);
        G8[g8f_addr(row0 + mi * 16 + r, col0 + ni * 16)] = q8;
        float gv = fp82f(q8);
        nsum[mi][r] += gv * gv;
      }
#pragma unroll
  for (int off = 1; off < 16; off <<= 1)
#pragma unroll
    for (int mi = 0; mi < 4; mi++)
#pragma unroll
      for (int r = 0; r < 4; r++) nsum[mi][r] += __shfl_xor(nsum[mi][r], off, 64);
  if ((lane & 15) == 0) {
#pragma unroll
    for (int mi = 0; mi < 4; mi++)
#pragma unroll
      for (int r = 0; r < 4; r++)
        atomicAdd(&diag[row0 + mi * 16 + r], nsum[mi][r]);
  }
}

// ---------- GEMM2 symmetric fp8, barrier-free, depth-8 pipeline, nt P stores ----------
__global__ __launch_bounds__(256) void gemm2_sym(
    const unsigned char* __restrict__ G8, const float* __restrict__ diag,
    unsigned short* __restrict__ P, float* __restrict__ l,
    unsigned int* __restrict__ flags) {
  int rem = blockIdx.x, br = 0;
  while (rem >= 32 - br) { rem -= 32 - br; ++br; }
  const int bc = br + rem;

  const int tid = threadIdx.x, lane = tid & 63, wave = tid >> 6;
  const int waveM = wave >> 1, waveN = wave & 1;
  const long rowA0 = (long)br * 128;
  const long rowB0 = (long)bc * 128;

  __shared__ unsigned int nzsh[4], nzmsh[4];

  const long rbA0 = (rowA0 >> 4) + waveM * 4;
  const long rbB0 = (rowB0 >> 4) + waveN * 4;
  const unsigned char* pA[4];
  const unsigned char* pB[4];
#pragma unroll
  for (int i = 0; i < 4; i++) {
    pA[i] = G8 + (rbA0 + i) * 16384 + lane * 8;
    pB[i] = G8 + (rbB0 + i) * 16384 + lane * 8;
  }

  f32x4 acc[4][4];
#pragma unroll
  for (int i = 0; i < 4; i++)
#pragma unroll
    for (int j = 0; j < 4; j++)
#pragma unroll
      for (int r = 0; r < 4; r++) acc[i][j][r] = 0.f;

  // depth-8 rotating fragment buffers (64 coalesced loads in flight)
  long fa[8][4], fb[8][4];
#pragma unroll
  for (int p = 0; p < 8; p++) {
#pragma unroll
    for (int i = 0; i < 4; i++) fa[p][i] = *(const long*)(pA[i] + p * 512);
#pragma unroll
    for (int i = 0; i < 4; i++) fb[p][i] = *(const long*)(pB[i] + p * 512);
  }

  for (int it = 0; it < 32; it += 8) {
#pragma unroll
    for (int p = 0; p < 8; p++) {
#pragma unroll
      for (int mi = 0; mi < 4; mi++)
#pragma unroll
        for (int ni = 0; ni < 4; ni++)
          acc[mi][ni] = __builtin_amdgcn_mfma_f32_16x16x32_fp8_fp8(
              fa[p][mi], fb[p][ni], acc[mi][ni], 0, 0, 0);
      const int kn = (it + p + 8) * 512;   // tail over-read stays in ws slack
#pragma unroll
      for (int i = 0; i < 4; i++) fa[p][i] = *(const long*)(pA[i] + kn);
#pragma unroll
      for (int i = 0; i < 4; i++) fb[p][i] = *(const long*)(pB[i] + kn);
    }
  }

  const long row0 = rowA0 + waveM * 64 + (lane >> 4) * 4;
  const long col0 = rowB0 + waveN * 64 + (lane & 15);

  float drow[4][4], dcol[4];
#pragma unroll
  for (int mi = 0; mi < 4; mi++)
#pragma unroll
    for (int r = 0; r < 4; r++) drow[mi][r] = diag[row0 + mi * 16 + r];
#pragma unroll
  for (int ni = 0; ni < 4; ni++) dcol[ni] = diag[col0 + ni * 16];

  bool myP = false, myM = false;
#pragma unroll
  for (int mi = 0; mi < 4; mi++)
#pragma unroll
    for (int ni = 0; ni < 4; ni++)
#pragma unroll
      for (int r = 0; r < 4; r++) {
        myP |= (acc[mi][ni][r] - drow[mi][r] > -88.0f);
        myM |= (acc[mi][ni][r] - dcol[ni]   > -88.0f);
      }
  const unsigned int wnzP = (__ballot(myP) != 0ull) ? 1u : 0u;
  const unsigned int wnzM = (__ballot(myM) != 0ull) ? 1u : 0u;
  if (lane == 0) { nzsh[wave] = wnzP; nzmsh[wave] = wnzM; }
  __syncthreads();
  const bool pairP = (nzsh[waveN] | nzsh[2 + waveN]) != 0u;
  const bool pairM = (nzmsh[waveM * 2] | nzmsh[waveM * 2 + 1]) != 0u;

  if (pairP) {
    if (wnzP) {
      float lsum[4][4];
#pragma unroll
      for (int mi = 0; mi < 4; mi++)
#pragma unroll
        for (int r = 0; r < 4; r++) lsum[mi][r] = 0.f;
#pragma unroll
      for (int mi = 0; mi < 4; mi++)
#pragma unroll
        for (int ni = 0; ni < 4; ni++)
#pragma unroll
          for (int r = 0; r < 4; r++) {
            float pv = __expf(acc[mi][ni][r] - drow[mi][r]);
            unsigned short p16 = f2bf(pv);
            lsum[mi][r] += bf2f(p16);
            __builtin_nontemporal_store(p16, &P[(row0 + mi * 16 + r) * 4096 + col0 + ni * 16]);
          }
#pragma unroll
      for (int off = 1; off < 16; off <<= 1)
#pragma unroll
        for (int mi = 0; mi < 4; mi++)
#pragma unroll
          for (int r = 0; r < 4; r++) lsum[mi][r] += __shfl_xor(lsum[mi][r], off, 64);
      if ((lane & 15) == 0) {
#pragma unroll
        for (int mi = 0; mi < 4; mi++)
#pragma unroll
          for (int r = 0; r < 4; r++)
            atomicAdd(&l[row0 + mi * 16 + r], lsum[mi][r]);
      }
    } else {
      unsigned short z16 = 0;
#pragma unroll
      for (int mi = 0; mi < 4; mi++)
#pragma unroll
        for (int ni = 0; ni < 4; ni++)
#pragma unroll
          for (int r = 0; r < 4; r++)
            __builtin_nontemporal_store(z16, &P[(row0 + mi * 16 + r) * 4096 + col0 + ni * 16]);
    }
    if (waveM == 0 && lane == 0) {
      const int tile = bc * 2 + waveN;
      atomicOr(&flags[br * 2 + (tile >> 5)], 1u << (tile & 31));
    }
  }

  if (bc > br && pairM) {
    if (wnzM) {
      float csum[4];
#pragma unroll
      for (int ni = 0; ni < 4; ni++) csum[ni] = 0.f;
#pragma unroll
      for (int mi = 0; mi < 4; mi++)
#pragma unroll
        for (int ni = 0; ni < 4; ni++) {
          us4n o;
          unsigned short x;
          float pv;
          pv = __expf(acc[mi][ni][0] - dcol[ni]); x = f2bf(pv); csum[ni] += bf2f(x); o.x = x;
          pv = __expf(acc[mi][ni][1] - dcol[ni]); x = f2bf(pv); csum[ni] += bf2f(x); o.y = x;
          pv = __expf(acc[mi][ni][2] - dcol[ni]); x = f2bf(pv); csum[ni] += bf2f(x); o.z = x;
          pv = __expf(acc[mi][ni][3] - dcol[ni]); x = f2bf(pv); csum[ni] += bf2f(x); o.w = x;
          __builtin_nontemporal_store(o, (us4n*)(P + (col0 + ni * 16) * 4096 + row0 + mi * 16));
        }
#pragma unroll
      for (int ni = 0; ni < 4; ni++) {
        csum[ni] += __shfl_xor(csum[ni], 16, 64);
        csum[ni] += __shfl_xor(csum[ni], 32, 64);
      }
      if (lane < 16) {
#pragma unroll
        for (int ni = 0; ni < 4; ni++)
          atomicAdd(&l[col0 + ni * 16], csum[ni]);
      }
    } else {
      us4n z = {0, 0, 0, 0};
#pragma unroll
      for (int mi = 0; mi < 4; mi++)
#pragma unroll
        for (int ni = 0; ni < 4; ni++)
          __builtin_nontemporal_store(z, (us4n*)(P + (col0 + ni * 16) * 4096 + row0 + mi * 16));
    }
    if (waveN == 0 && lane == 0) {
      const int tile = br * 2 + waveM;
      atomicOr(&flags[bc * 2 + (tile >> 5)], 1u << (tile & 31));
    }
  }
}

// ---------- GEMM3 sparse: Z = (P @ Y) / l, skipping all-zero P tiles (exact) ----------
__global__ __launch_bounds__(256) void gemm3_sparse(
    const unsigned short* __restrict__ P, const unsigned short* __restrict__ Ybt,
    const float* __restrict__ l, const unsigned int* __restrict__ flags,
    float* __restrict__ Z) {
  __shared__ __align__(16) unsigned short smA[128 * 32];
  __shared__ __align__(16) unsigned short smB[64 * 32];
  const int tid = threadIdx.x, lane = tid & 63, wave = tid >> 6;
  const int waveM = wave >> 1, waveN = wave & 1;
  const long rowA0 = (long)blockIdx.y * 128;
  const long rowB0 = (long)blockIdx.x * 64;

  const int rS = tid >> 2;
  const int kS = (tid & 3) ^ swz(rS);
  const unsigned short* gA0 = P + (rowA0 + rS) * 4096 + kS * 8;
  const unsigned short* gA1 = gA0 + 64 * 4096;
  unsigned short* lA0 = &smA[tid * 8];
  const unsigned short* gB0 = Ybt + (rowB0 + rS) * 4096 + kS * 8;
  unsigned short* lB0 = &smB[tid * 8];

  const int ra = waveM * 64 + (lane & 15);
  const int rb = waveN * 32 + (lane & 15);
  const unsigned short* pa = &smA[(ra * 4 + ((lane >> 4) ^ swz(ra))) * 8];
  const unsigned short* pb = &smB[(rb * 4 + ((lane >> 4) ^ swz(rb))) * 8];

  const unsigned int f0 = flags[blockIdx.y * 2];
  const unsigned int f1 = flags[blockIdx.y * 2 + 1];

  f32x4 acc[4][2];
#pragma unroll
  for (int i = 0; i < 4; i++)
#pragma unroll
    for (int j = 0; j < 2; j++)
#pragma unroll
      for (int r = 0; r < 4; r++) acc[i][j][r] = 0.f;

  for (int t = 0; t < 64; ++t) {
    const unsigned int bit = (t < 32) ? ((f0 >> t) & 1u) : ((f1 >> (t - 32)) & 1u);
    if (!bit) continue;
#pragma unroll
    for (int kk = 0; kk < 2; ++kk) {
      const int k0 = t * 64 + kk * 32;
      __syncthreads();
      gld_lds16(gA0 + k0, lA0);
      gld_lds16(gA1 + k0, lA0 + 2048);
      gld_lds16(gB0 + k0, lB0);
      __syncthreads();
      bf16x8 af[4], bfv[2];
#pragma unroll
      for (int i = 0; i < 4; i++) af[i] = *(const bf16x8*)(pa + i * 512);
#pragma unroll
      for (int j = 0; j < 2; j++) bfv[j] = *(const bf16x8*)(pb + j * 512);
#pragma unroll
      for (int mi = 0; mi < 4; mi++)
#pragma unroll
        for (int ni = 0; ni < 2; ni++)
          acc[mi][ni] = __builtin_amdgcn_mfma_f32_16x16x32_bf16(af[mi], bfv[ni], acc[mi][ni], 0, 0, 0);
    }
  }

  const long row0 = rowA0 + waveM * 64 + (lane >> 4) * 4;
  const long col0 = rowB0 + waveN * 32 + (lane & 15);
#pragma unroll
  for (int mi = 0; mi < 4; mi++)
#pragma unroll
    for (int r = 0; r < 4; r++) {
      const long row = row0 + mi * 16 + r;
      const float inv = 1.f / l[row];
#pragma unroll
      for (int ni = 0; ni < 2; ni++)
        Z[row * 1024 + col0 + ni * 16] = acc[mi][ni][r] * inv;
    }
}

// ---------- launch ----------
extern "C" void kernel_launch(void* const* d_in, const int* in_sizes, int n_in,
                              void* d_out, int out_size, void* d_ws, size_t ws_size,
                              hipStream_t stream) {
  const float* Y = (const float*)d_in[0];   // 4096 x 1024
  const float* W = (const float*)d_in[1];   // 1024 x 1024
  float* Z = (float*)d_out;                 // 4096 x 1024 fp32

  uint8_t* w = (uint8_t*)d_ws;
  unsigned short* Ybf  = (unsigned short*)(w);                         // 8 MB bf16 fragment-linear
  unsigned short* Ybt  = (unsigned short*)(w + (8ull  << 20));         // 8 MB bf16 transposed
  unsigned short* Wbf  = (unsigned short*)(w + (16ull << 20));         // 2 MB bf16 fragment-linear
  unsigned char*  G8   = (unsigned char*) (w + (18ull << 20));         // 4 MB fp8 fragment-linear
  unsigned short* P    = (unsigned short*)(w + (26ull << 20));         // 32 MB
  float*          diag = (float*)         (w + (58ull << 20));         // 16 KB
  float*          lrow = (float*)         (w + (58ull << 20) + 16384); // 16 KB
  unsigned int*   flg  = (unsigned int*)  (w + (58ull << 20) + 32768); // 256 B

  convert_all<<<dim3(64, 17), 256, 0, stream>>>(Y, Ybf, Ybt, W, Wbf, diag);

  // G8f = fp8(Y W^T) + diag; barrier-free coalesced pipeline
  gemm1_fused<<<dim3(16, 32), 256, 0, stream>>>(Ybf, Wbf, G8, diag);

  // P = exp(G8 G8^T - diag[row]); triangle grid, depth-8 pipeline, nt stores
  gemm2_sym<<<528, 256, 0, stream>>>(G8, diag, P, lrow, flg);

  // Z = (P @ Y) / l with exact zero-tile skipping
  gemm3_sparse<<<dim3(16, 32), 256, 0, stream>>>(P, Ybt, lrow, flg, Z);
}